// Round 15
// baseline (1192.902 us; speedup 1.0000x reference)
//
#include <hip/hip_runtime.h>
#include <hip/hip_bf16.h>

#define NA 100000
#define NB 400000
#define NG 5000
#define NEG 0.2f
#define KDIM 512
#define CAP 32          // max in-degree slots (fixed input graph: 1+Binom; P(>32)~0)
#define NBINS 33        // cc in [0,32]
#define FG_BLKS 782     // ceil(NA/128)
#define KSC_BLKS 7891   // ceil(505008/64); covers 505024 row slots

typedef __attribute__((ext_vector_type(8))) short bf16x8;
typedef __attribute__((ext_vector_type(8))) unsigned short u16x8;
typedef __attribute__((ext_vector_type(4))) float f32x4;

__device__ __forceinline__ float lrelu(float x){ return x > 0.f ? x : NEG*x; }
__device__ __forceinline__ unsigned short f2bf(float f){
  unsigned u = __float_as_uint(f);
  u = (u + 0x7FFFu + ((u>>16)&1u)) >> 16;
  return (unsigned short)u;
}
__device__ __forceinline__ float bf2f(unsigned short s){
  return __uint_as_float(((unsigned)s) << 16);
}
__device__ __forceinline__ ushort2 pk2(float x, float y){
  __hip_bfloat162 t = __float22bfloat162_rn(make_float2(x, y));
  return *reinterpret_cast<ushort2*>(&t);
}

// ---------------- kW: weight prep ----------------
__global__ void kW(const float* __restrict__ Wa, const float* __restrict__ Wb,
                   const float* __restrict__ Wg, const float* __restrict__ glob,
                   const float* __restrict__ al, const float* __restrict__ ar,
                   unsigned short* wTa, unsigned short* wTb, unsigned short* wTu,
                   unsigned short* WcT, unsigned short* P){
  int blk = blockIdx.x;
  int tid = threadIdx.x;
  if (blk == 0){
    int k = tid >> 1, h = tid & 1;
    const float* wa = Wa + k*256 + h*128;
    const float* wb = Wb + k*256 + h*128;
    const float* wg = Wg + k*256 + h*128;
    const float* pl = al + h*128;
    const float* pr = ar + h*128;
    float sa=0.f, sra=0.f, se=0.f, su=0.f;
    for (int d=0; d<128; ++d){
      float L = pl[d], R = pr[d];
      sa  += wa[d]*L;  sra += wa[d]*R;
      se  += wb[d]*L;  su  += wg[d]*L;
    }
    wTa[h*128 + k]     = f2bf(sa);
    wTa[(2+h)*128 + k] = f2bf(sra);
    wTb[h*128 + k]     = f2bf(se);
    wTu[h*128 + k]     = f2bf(su);
    for (int idx = tid; idx < 14*128; idx += 256){
      int c = 2 + (idx >> 7), k2 = idx & 127;
      wTb[c*128 + k2] = 0;
      wTu[c*128 + k2] = 0;
      if (c >= 4) wTa[c*128 + k2] = 0;
    }
  } else if (blk <= 256){
    int idx = (blk-1)*256 + tid;            // 65536 = 128*KDIM
    int c = idx / KDIM, j = idx % KDIM;
    int part = j >> 7, k = j & 127;
    const float* W = (part < 2) ? Wa : Wb;
    int h = part & 1;
    WcT[(size_t)c*KDIM + j] = f2bf(0.5f * W[k*256 + h*128 + c]);
  } else {
    __shared__ float gl[8][128];
    int g0 = (blk-257)*8;                   // 625 blocks
    #pragma unroll
    for (int r=0;r<4;++r){
      int idx = r*256+tid;
      gl[idx>>7][idx&127] = glob[(size_t)(g0 + (idx>>7))*128 + (idx&127)];
    }
    __syncthreads();
    float acc[8];
    #pragma unroll
    for (int g=0;g<8;++g) acc[g]=0.f;
    for (int k=0;k<128;++k){
      float wv = Wg[k*256 + tid];
      #pragma unroll
      for (int g=0;g<8;++g) acc[g] += gl[g][k]*wv;
    }
    #pragma unroll
    for (int g=0;g<8;++g)
      P[(size_t)(g0+g)*256 + tid] = f2bf(0.5f*acc[g]);
  }
}

// ---------------- kSC: fused convert + MFMA score GEMM ----------------
__global__ __launch_bounds__(256) void kSC(
    const float* __restrict__ atom, const float* __restrict__ bond,
    const float* __restrict__ glob,
    const unsigned short* __restrict__ wTa, const unsigned short* __restrict__ wTb,
    const unsigned short* __restrict__ wTu,
    float* __restrict__ el_h, float* __restrict__ er,
    float* __restrict__ el_e, float* __restrict__ el_u,
    unsigned short* __restrict__ atomB, unsigned short* __restrict__ bondB){
  __shared__ unsigned short lds[4][16*128];   // 16 KB
  const int wid = threadIdx.x >> 6;
  const int l = threadIdx.x & 63;
  const long rowbase = ((long)blockIdx.x*4 + wid) * 16;

  const float* feats; const unsigned short* wT; unsigned short* fb;
  long r0; long nrows; int type;
  if (rowbase < NA){            feats = atom; wT = wTa; fb = atomB; r0 = rowbase;          nrows = NA; type = 0; }
  else if (rowbase < NA+NB){    feats = bond; wT = wTb; fb = bondB; r0 = rowbase-NA;       nrows = NB; type = 1; }
  else {                        feats = glob; wT = wTu; fb = nullptr; r0 = rowbase-(NA+NB); nrows = NG; type = 2; }

  bf16x8 bfrag[4];
  #pragma unroll
  for (int kk=0;kk<4;++kk)
    bfrag[kk] = *reinterpret_cast<const bf16x8*>(wT + (size_t)(l&15)*128 + kk*32 + (l>>4)*8);

  unsigned short* wlds = lds[wid];
  const int j = l & 15;       // 8-elem chunk within row
  const int rl0 = l >> 4;     // row subgroup
  #pragma unroll
  for (int i=0;i<4;++i){
    int rl = rl0 + i*4;                    // local row 0..15
    long gr = r0 + rl;
    long grc = gr < nrows ? gr : (nrows-1);
    const float* src = feats + grc*128 + j*8;
    float4 x0 = *reinterpret_cast<const float4*>(src);
    float4 x1 = *reinterpret_cast<const float4*>(src+4);
    u16x8 w;
    ushort2 c0 = pk2(x0.x, x0.y), c1 = pk2(x0.z, x0.w);
    ushort2 c2 = pk2(x1.x, x1.y), c3 = pk2(x1.z, x1.w);
    w[0]=c0.x; w[1]=c0.y; w[2]=c1.x; w[3]=c1.y;
    w[4]=c2.x; w[5]=c2.y; w[6]=c3.x; w[7]=c3.y;
    *reinterpret_cast<u16x8*>(&wlds[rl*128 + ((j ^ (rl&7))*8)]) = w;
    if (fb && gr < nrows)
      *reinterpret_cast<u16x8*>(fb + grc*128 + j*8) = w;
  }
  __syncthreads();

  f32x4 acc = (f32x4){0.f,0.f,0.f,0.f};
  const int arow = l & 15;
  #pragma unroll
  for (int kk=0;kk<4;++kk){
    int ch = (kk*4 + (l>>4)) ^ (arow & 7);
    bf16x8 a = *reinterpret_cast<const bf16x8*>(&wlds[arow*128 + ch*8]);
    acc = __builtin_amdgcn_mfma_f32_16x16x32_bf16(a, bfrag[kk], acc, 0, 0, 0);
  }

  const int col = l & 15;
  if (col < 4 && (type == 0 || col < 2)){
    #pragma unroll
    for (int i=0;i<4;++i){
      long gr = r0 + (l>>4)*4 + i;
      if (gr < nrows){
        float v = acc[i];
        if (type == 0){
          if (col < 2) el_h[2*gr + col] = v;
          else         er[2*gr + col-2] = v;
        } else if (type == 1){
          el_e[2*gr + col] = v;
        } else {
          el_u[2*gr + col] = v;
        }
      }
    }
  }
}

// ---------------- k4: per-bond exp scores + esum atomics + slot scatter ----------------
__global__ void k4_edgeexp(const int* __restrict__ bsrc, const int* __restrict__ bdst,
                           const float* __restrict__ el_h, const float* __restrict__ er,
                           const float* __restrict__ el_e,
                           int2* __restrict__ slot_bs, float4* __restrict__ slot_e,
                           int* __restrict__ cursor, float* __restrict__ esum){
  int b = blockIdx.x*256 + threadIdx.x;
  if (b >= NB) return;
  int s = bsrc[b], d = bdst[b];
  float2 elh = *reinterpret_cast<const float2*>(&el_h[2*s]);
  float2 erd = *reinterpret_cast<const float2*>(&er[2*d]);
  float2 ele = *reinterpret_cast<const float2*>(&el_e[2*b]);
  float a0 = __expf(lrelu(elh.x + erd.x));
  float a1 = __expf(lrelu(elh.y + erd.y));
  float b0 = __expf(lrelu(ele.x + erd.x));
  float b1 = __expf(lrelu(ele.y + erd.y));
  int pos = atomicAdd(&cursor[d], 1);
  if (pos < CAP){
    slot_bs[(size_t)d*CAP + pos] = make_int2(b, s);
    slot_e [(size_t)d*CAP + pos] = make_float4(a0, a1, b0, b1);
  }
  atomicAdd(&esum[2*d],   a0 + b0);
  atomicAdd(&esum[2*d+1], a1 + b1);
}

// ---------------- kPre: per-atom record + degree histogram ----------------
__global__ void kPre(const int* __restrict__ cursor, const float* __restrict__ esum,
                     const float* __restrict__ el_u, const float* __restrict__ er,
                     const int* __restrict__ g2a,
                     float4* __restrict__ recF, int* __restrict__ recC,
                     int* __restrict__ binCnt){
  int n = blockIdx.x*256 + threadIdx.x;
  if (n >= NA) return;
  int cc = cursor[n]; cc = cc > CAP ? CAP : cc;
  int g = g2a[n];
  float2 elu = *reinterpret_cast<const float2*>(&el_u[2*g]);
  float2 ern = *reinterpret_cast<const float2*>(&er[2*n]);
  float u0 = __expf(lrelu(elu.x + ern.x));
  float u1 = __expf(lrelu(elu.y + ern.y));
  float iv0 = 1.f/(esum[2*n]   + u0);
  float iv1 = 1.f/(esum[2*n+1] + u1);
  recF[n] = make_float4(iv0, iv1, u0*iv0, u1*iv1);
  recC[n] = cc;
  atomicAdd(&binCnt[cc], 1);
}

// ---------------- kScan: exclusive prefix over 33 degree bins ----------------
__global__ void kScan(const int* __restrict__ binCnt, int* __restrict__ binOff){
  if (threadIdx.x == 0){
    int acc = 0;
    for (int i=0;i<NBINS;++i){ binOff[i] = acc; acc += binCnt[i]; }
  }
}

// ---------------- kScat: scatter atoms into degree-sorted perm ----------------
__global__ void kScat(const int* __restrict__ recC, const int* __restrict__ binOff,
                      int* __restrict__ binCur, int* __restrict__ perm){
  int n = blockIdx.x*256 + threadIdx.x;
  if (n >= NA) return;
  int cc = recC[n];
  int pos = binOff[cc] + atomicAdd(&binCur[cc], 1);
  perm[pos] = n;
}

// ---------------- kFG v9: v6 structure + degree-sorted atom order ----------------
// BM=128, XA[128][256] reused across phase A/B, 4-deep branchless gather.
// Atoms processed in perm order -> the 4 groups of each wave share (nearly)
// identical cc -> no exec-masked divergence waste in the j-loop.
__global__ __launch_bounds__(512, 4) void kFG(
    const unsigned short* __restrict__ atomB,
    const unsigned short* __restrict__ bondB,
    const int2* __restrict__ slot_bs, const float4* __restrict__ slot_e,
    const float4* __restrict__ recF, const int* __restrict__ recC,
    const int* __restrict__ perm,
    const int* __restrict__ g2a,
    const unsigned short* __restrict__ WcT,
    const unsigned short* __restrict__ P,
    float* __restrict__ out, float* __restrict__ colsum, float* __restrict__ colsq){
  __shared__ unsigned short XA[128*256];   // 64 KB, chunk-XOR swizzled
  __shared__ float au_s[128][2];           // 1 KB
  __shared__ int   prm_s[128];
  const int tid = threadIdx.x;
  const int l  = tid & 63;
  const int li = tid & 15;
  const int gid = tid >> 4;        // 0..31 (group of 16 lanes = one feature row)
  const int w = tid >> 6;          // 0..7
  const int wr = w >> 2, wc = w & 3;
  const int gb = l & 48;           // group base lane within wave
  const int n0 = blockIdx.x * 128;

  f32x4 acc[4][2];
  #pragma unroll
  for (int m=0;m<4;++m)
    #pragma unroll
    for (int nf=0;nf<2;++nf) acc[m][nf] = (f32x4){0.f,0.f,0.f,0.f};

  auto agg = [&](int phase){
    for (int t=0; t<4; ++t){
      int ln = gid + t*32;
      int pn = n0 + ln;
      float a0[8], a1[8];
      #pragma unroll
      for (int k2=0;k2<8;++k2){ a0[k2]=0.f; a1[k2]=0.f; }
      int cc = 0; float iv0=0.f, iv1=0.f;
      int n = 0;
      if (pn < NA){
        n = perm[pn];
        cc = recC[n];
        float4 rec = recF[n];
        iv0 = rec.x; iv1 = rec.y;
        if (phase==0 && li==0){ au_s[ln][0]=rec.z; au_s[ln][1]=rec.w; prm_s[ln]=n; }
      }
      // slot metadata: lanes li cover slots 0..15 (A), li+16 -> 16..31 (B)
      int idxA=0, idxB=0; float w0A=0.f,w1A=0.f,w0B=0.f,w1B=0.f;
      if (li < cc){
        int2 bs = slot_bs[(size_t)n*CAP + li];
        float4 e = slot_e[(size_t)n*CAP + li];
        idxA = phase ? bs.x : bs.y;
        w0A = phase ? e.z : e.x;
        w1A = phase ? e.w : e.y;
      }
      if (li+16 < cc){
        int2 bs = slot_bs[(size_t)n*CAP + li+16];
        float4 e = slot_e[(size_t)n*CAP + li+16];
        idxB = phase ? bs.x : bs.y;
        w0B = phase ? e.z : e.x;
        w1B = phase ? e.w : e.y;
      }
      const unsigned short* tbl = phase ? bondB : atomB;
      if (cc > 0){
        const int last = cc - 1;
        // branchless clamped slot index (loads always valid)
        #define IDXJ(J) ({ int _jj = (J) <= last ? (J) : last; \
                           int _sl = gb + (_jj & 15); \
                           (_jj < 16) ? __shfl(idxA, _sl) : __shfl(idxB, _sl); })
        u16x8 x0 = *reinterpret_cast<const u16x8*>(tbl + (size_t)IDXJ(0)*128 + li*8);
        u16x8 x1 = *reinterpret_cast<const u16x8*>(tbl + (size_t)IDXJ(1)*128 + li*8);
        u16x8 x2 = *reinterpret_cast<const u16x8*>(tbl + (size_t)IDXJ(2)*128 + li*8);
        u16x8 x3 = *reinterpret_cast<const u16x8*>(tbl + (size_t)IDXJ(3)*128 + li*8);
        for (int j0 = 0; j0 < cc; j0 += 4){
          u16x8 y0=x0, y1=x1, y2=x2, y3=x3;
          x0 = *reinterpret_cast<const u16x8*>(tbl + (size_t)IDXJ(j0+4)*128 + li*8);
          x1 = *reinterpret_cast<const u16x8*>(tbl + (size_t)IDXJ(j0+5)*128 + li*8);
          x2 = *reinterpret_cast<const u16x8*>(tbl + (size_t)IDXJ(j0+6)*128 + li*8);
          x3 = *reinterpret_cast<const u16x8*>(tbl + (size_t)IDXJ(j0+7)*128 + li*8);
          #define CONSUME(YY, JJ) { \
            int _j = j0 + (JJ); \
            int _jc = _j <= last ? _j : last; \
            int _sl = gb + (_jc & 15); \
            float _w0 = (_jc < 16) ? __shfl(w0A, _sl) : __shfl(w0B, _sl); \
            float _w1 = (_jc < 16) ? __shfl(w1A, _sl) : __shfl(w1B, _sl); \
            float _c0 = (_j <= last) ? _w0*iv0 : 0.f; \
            float _c1 = (_j <= last) ? _w1*iv1 : 0.f; \
            _Pragma("unroll") \
            for (int k2=0;k2<8;++k2){ \
              float _v = bf2f((YY)[k2]); \
              a0[k2] += _c0*_v; a1[k2] += _c1*_v; \
            } }
          CONSUME(y0, 0)
          CONSUME(y1, 1)
          CONSUME(y2, 2)
          CONSUME(y3, 3)
          #undef CONSUME
        }
        #undef IDXJ
      }
      u16x8 o0, o1;
      #pragma unroll
      for (int k2=0;k2<8;++k2){ o0[k2]=f2bf(a0[k2]); o1[k2]=f2bf(a1[k2]); }
      *reinterpret_cast<u16x8*>(&XA[ln*256 + ((li   ) ^ (ln&7))*8]) = o0;
      *reinterpret_cast<u16x8*>(&XA[ln*256 + ((16+li) ^ (ln&7))*8]) = o1;
    }
  };

  auto gemm = [&](int phase){
    #pragma unroll
    for (int ks=0; ks<8; ++ks){
      bf16x8 av[4], bv[2];
      #pragma unroll
      for (int m=0;m<4;++m){
        int row = wr*64 + m*16 + (l&15);
        int ch = (ks*4 + (l>>4)) ^ (row&7);
        av[m] = *reinterpret_cast<const bf16x8*>(&XA[row*256 + ch*8]);
      }
      #pragma unroll
      for (int nf=0;nf<2;++nf){
        int col = wc*32 + nf*16 + (l&15);
        bv[nf] = *reinterpret_cast<const bf16x8*>(
            WcT + (size_t)col*KDIM + phase*256 + ks*32 + (l>>4)*8);
      }
      #pragma unroll
      for (int m=0;m<4;++m)
        #pragma unroll
        for (int nf=0;nf<2;++nf)
          acc[m][nf] = __builtin_amdgcn_mfma_f32_16x16x32_bf16(av[m], bv[nf], acc[m][nf], 0, 0, 0);
    }
  };

  agg(0);
  __syncthreads();
  gemm(0);
  __syncthreads();
  agg(1);
  __syncthreads();
  gemm(1);

  // epilogue: + global term, store (perm-scattered rows), fused column stats
  float s[2] = {0.f,0.f};
  float q[2] = {0.f,0.f};
  #pragma unroll
  for (int m=0;m<4;++m){
    #pragma unroll
    for (int i=0;i<4;++i){
      int row_l = wr*64 + m*16 + (l>>4)*4 + i;
      int pn = n0 + row_l;
      if (pn < NA){
        size_t row = (size_t)prm_s[row_l];
        float aux = au_s[row_l][0], auy = au_s[row_l][1];
        int g = g2a[row];
        const unsigned short* Pg = P + (size_t)g*256;
        #pragma unroll
        for (int nf=0;nf<2;++nf){
          int col = wc*32 + nf*16 + (l&15);
          float v = acc[m][nf][i] + aux*bf2f(Pg[col]) + auy*bf2f(Pg[128+col]);
          out[row*128 + col] = v;
          s[nf] += v; q[nf] += v*v;
        }
      }
    }
  }
  #pragma unroll
  for (int nf=0;nf<2;++nf){
    int col = wc*32 + nf*16 + (l&15);
    float sv = s[nf], qv = q[nf];
    sv += __shfl_xor(sv, 16); sv += __shfl_xor(sv, 32);
    qv += __shfl_xor(qv, 16); qv += __shfl_xor(qv, 32);
    if (l < 16){
      atomicAdd(&colsum[col], sv);
      atomicAdd(&colsq[col],  qv);
    }
  }
}

// ---------------- k11: BN finalize + apply + ReLU ----------------
__global__ __launch_bounds__(256) void k11_bnrelu(float* __restrict__ out,
                            const float* __restrict__ colsum, const float* __restrict__ colsq,
                            const float* __restrict__ gamma, const float* __restrict__ beta){
  __shared__ float sc[128], sh[128];
  int t = threadIdx.x;
  if (t < 128){
    float mean = colsum[t] / (float)NA;
    float var = fmaxf(colsq[t] / (float)NA - mean*mean, 0.f);
    float s = gamma[t] * rsqrtf(var + 1e-5f);
    sc[t] = s;
    sh[t] = beta[t] - mean*s;
  }
  __syncthreads();
  int i = blockIdx.x*256 + t;   // 3.2M float4s exactly
  float4 v = reinterpret_cast<float4*>(out)[i];
  int c0 = (i*4) & 127;
  v.x = fmaxf(0.f, v.x*sc[c0]   + sh[c0]);
  v.y = fmaxf(0.f, v.y*sc[c0+1] + sh[c0+1]);
  v.z = fmaxf(0.f, v.z*sc[c0+2] + sh[c0+2]);
  v.w = fmaxf(0.f, v.w*sc[c0+3] + sh[c0+3]);
  reinterpret_cast<float4*>(out)[i] = v;
}

extern "C" void kernel_launch(void* const* d_in, const int* in_sizes, int n_in,
                              void* d_out, int out_size, void* d_ws, size_t ws_size,
                              hipStream_t stream) {
  const float* atom = (const float*)d_in[0];
  const float* bond = (const float*)d_in[1];
  const float* glob = (const float*)d_in[2];
  const float* Wa   = (const float*)d_in[3];
  const float* Wb   = (const float*)d_in[4];
  const float* Wg   = (const float*)d_in[5];
  const float* al   = (const float*)d_in[6];
  const float* ar   = (const float*)d_in[7];
  const float* gamma= (const float*)d_in[8];
  const float* beta = (const float*)d_in[9];
  const int* bsrc   = (const int*)d_in[10];
  const int* bdst   = (const int*)d_in[11];
  const int* g2a    = (const int*)d_in[12];
  float* out = (float*)d_out;

  char* base = (char*)d_ws;
  size_t off = 0;
  auto carve = [&](size_t bytes)->void*{
    void* p = base + off;
    off = (off + bytes + 255) & ~(size_t)255;
    return p;
  };
  unsigned short* wTa = (unsigned short*)carve((size_t)16*128*2);
  unsigned short* wTb = (unsigned short*)carve((size_t)16*128*2);
  unsigned short* wTu = (unsigned short*)carve((size_t)16*128*2);
  unsigned short* WcT = (unsigned short*)carve((size_t)128*KDIM*2);
  unsigned short* P   = (unsigned short*)carve((size_t)NG*256*2);
  float* el_h = (float*)carve((size_t)NA*2*4);
  float* er   = (float*)carve((size_t)NA*2*4);
  float* el_e = (float*)carve((size_t)NB*2*4);
  float* el_u = (float*)carve((size_t)NG*2*4);
  float4* recF = (float4*)carve((size_t)NA*16);
  int*    recC = (int*)carve((size_t)NA*4);
  int*    perm = (int*)carve((size_t)NA*4);
  int*    binOff = (int*)carve(64*4);
  // single zero-init region: [esum | cursor | colsum | colsq | binCnt | binCur]
  size_t zbytes = (size_t)NA*2*4 + (size_t)NA*4 + 256*4 + 128*4;
  char* zr = (char*)carve(zbytes);
  float* esum   = (float*)(zr);
  int*   cursor = (int*)(zr + (size_t)NA*2*4);
  float* colsum = (float*)(zr + (size_t)NA*2*4 + (size_t)NA*4);
  float* colsq  = colsum + 128;
  int*   binCnt = (int*)(zr + (size_t)NA*2*4 + (size_t)NA*4 + 256*4);
  int*   binCur = binCnt + 64;
  int2*   slot_bs = (int2*)carve((size_t)NA*CAP*8);
  float4* slot_e  = (float4*)carve((size_t)NA*CAP*16);
  unsigned short* atomB = (unsigned short*)carve((size_t)NA*128*2);
  unsigned short* bondB = (unsigned short*)carve((size_t)NB*128*2);

  hipMemsetAsync(zr, 0, zbytes, stream);

  kW<<<882, 256, 0, stream>>>(Wa, Wb, Wg, glob, al, ar, wTa, wTb, wTu, WcT, P);

  kSC<<<KSC_BLKS, 256, 0, stream>>>(atom, bond, glob, wTa, wTb, wTu,
                                    el_h, er, el_e, el_u, atomB, bondB);

  k4_edgeexp<<<1563, 256, 0, stream>>>(bsrc, bdst, el_h, er, el_e,
                                       slot_bs, slot_e, cursor, esum);

  kPre<<<391, 256, 0, stream>>>(cursor, esum, el_u, er, g2a, recF, recC, binCnt);
  kScan<<<1, 64, 0, stream>>>(binCnt, binOff);
  kScat<<<391, 256, 0, stream>>>(recC, binOff, binCur, perm);

  kFG<<<FG_BLKS, 512, 0, stream>>>(atomB, bondB, slot_bs, slot_e, recF, recC,
                                   perm, g2a, WcT, P, out, colsum, colsq);

  k11_bnrelu<<<12500, 256, 0, stream>>>(out, colsum, colsq, gamma, beta);
}

// Round 16
// 332.902 us; speedup vs baseline: 3.5833x; 3.5833x over previous
//
#include <hip/hip_runtime.h>
#include <hip/hip_bf16.h>

#define NA 100000
#define NB 400000
#define NG 5000
#define NEG 0.2f
#define KDIM 512
#define CAP 32          // max in-degree slots (fixed input graph: 1+Binom; P(>32)~0)
#define NBINS 33        // cc in [0,32]
#define FG_BLKS 782     // ceil(NA/128)
#define KSC_BLKS 7891   // ceil(505008/64); covers 505024 row slots

typedef __attribute__((ext_vector_type(8))) short bf16x8;
typedef __attribute__((ext_vector_type(8))) unsigned short u16x8;
typedef __attribute__((ext_vector_type(4))) float f32x4;

__device__ __forceinline__ float lrelu(float x){ return x > 0.f ? x : NEG*x; }
__device__ __forceinline__ unsigned short f2bf(float f){
  unsigned u = __float_as_uint(f);
  u = (u + 0x7FFFu + ((u>>16)&1u)) >> 16;
  return (unsigned short)u;
}
__device__ __forceinline__ float bf2f(unsigned short s){
  return __uint_as_float(((unsigned)s) << 16);
}
__device__ __forceinline__ ushort2 pk2(float x, float y){
  __hip_bfloat162 t = __float22bfloat162_rn(make_float2(x, y));
  return *reinterpret_cast<ushort2*>(&t);
}

// ---------------- kW: weight prep ----------------
__global__ void kW(const float* __restrict__ Wa, const float* __restrict__ Wb,
                   const float* __restrict__ Wg, const float* __restrict__ glob,
                   const float* __restrict__ al, const float* __restrict__ ar,
                   unsigned short* wTa, unsigned short* wTb, unsigned short* wTu,
                   unsigned short* WcT, unsigned short* P){
  int blk = blockIdx.x;
  int tid = threadIdx.x;
  if (blk == 0){
    int k = tid >> 1, h = tid & 1;
    const float* wa = Wa + k*256 + h*128;
    const float* wb = Wb + k*256 + h*128;
    const float* wg = Wg + k*256 + h*128;
    const float* pl = al + h*128;
    const float* pr = ar + h*128;
    float sa=0.f, sra=0.f, se=0.f, su=0.f;
    for (int d=0; d<128; ++d){
      float L = pl[d], R = pr[d];
      sa  += wa[d]*L;  sra += wa[d]*R;
      se  += wb[d]*L;  su  += wg[d]*L;
    }
    wTa[h*128 + k]     = f2bf(sa);
    wTa[(2+h)*128 + k] = f2bf(sra);
    wTb[h*128 + k]     = f2bf(se);
    wTu[h*128 + k]     = f2bf(su);
    for (int idx = tid; idx < 14*128; idx += 256){
      int c = 2 + (idx >> 7), k2 = idx & 127;
      wTb[c*128 + k2] = 0;
      wTu[c*128 + k2] = 0;
      if (c >= 4) wTa[c*128 + k2] = 0;
    }
  } else if (blk <= 256){
    int idx = (blk-1)*256 + tid;            // 65536 = 128*KDIM
    int c = idx / KDIM, j = idx % KDIM;
    int part = j >> 7, k = j & 127;
    const float* W = (part < 2) ? Wa : Wb;
    int h = part & 1;
    WcT[(size_t)c*KDIM + j] = f2bf(0.5f * W[k*256 + h*128 + c]);
  } else {
    __shared__ float gl[8][128];
    int g0 = (blk-257)*8;                   // 625 blocks
    #pragma unroll
    for (int r=0;r<4;++r){
      int idx = r*256+tid;
      gl[idx>>7][idx&127] = glob[(size_t)(g0 + (idx>>7))*128 + (idx&127)];
    }
    __syncthreads();
    float acc[8];
    #pragma unroll
    for (int g=0;g<8;++g) acc[g]=0.f;
    for (int k=0;k<128;++k){
      float wv = Wg[k*256 + tid];
      #pragma unroll
      for (int g=0;g<8;++g) acc[g] += gl[g][k]*wv;
    }
    #pragma unroll
    for (int g=0;g<8;++g)
      P[(size_t)(g0+g)*256 + tid] = f2bf(0.5f*acc[g]);
  }
}

// ---------------- kSC: fused convert + MFMA score GEMM ----------------
__global__ __launch_bounds__(256) void kSC(
    const float* __restrict__ atom, const float* __restrict__ bond,
    const float* __restrict__ glob,
    const unsigned short* __restrict__ wTa, const unsigned short* __restrict__ wTb,
    const unsigned short* __restrict__ wTu,
    float* __restrict__ el_h, float* __restrict__ er,
    float* __restrict__ el_e, float* __restrict__ el_u,
    unsigned short* __restrict__ atomB, unsigned short* __restrict__ bondB){
  __shared__ unsigned short lds[4][16*128];   // 16 KB
  const int wid = threadIdx.x >> 6;
  const int l = threadIdx.x & 63;
  const long rowbase = ((long)blockIdx.x*4 + wid) * 16;

  const float* feats; const unsigned short* wT; unsigned short* fb;
  long r0; long nrows; int type;
  if (rowbase < NA){            feats = atom; wT = wTa; fb = atomB; r0 = rowbase;          nrows = NA; type = 0; }
  else if (rowbase < NA+NB){    feats = bond; wT = wTb; fb = bondB; r0 = rowbase-NA;       nrows = NB; type = 1; }
  else {                        feats = glob; wT = wTu; fb = nullptr; r0 = rowbase-(NA+NB); nrows = NG; type = 2; }

  bf16x8 bfrag[4];
  #pragma unroll
  for (int kk=0;kk<4;++kk)
    bfrag[kk] = *reinterpret_cast<const bf16x8*>(wT + (size_t)(l&15)*128 + kk*32 + (l>>4)*8);

  unsigned short* wlds = lds[wid];
  const int j = l & 15;       // 8-elem chunk within row
  const int rl0 = l >> 4;     // row subgroup
  #pragma unroll
  for (int i=0;i<4;++i){
    int rl = rl0 + i*4;                    // local row 0..15
    long gr = r0 + rl;
    long grc = gr < nrows ? gr : (nrows-1);
    const float* src = feats + grc*128 + j*8;
    float4 x0 = *reinterpret_cast<const float4*>(src);
    float4 x1 = *reinterpret_cast<const float4*>(src+4);
    u16x8 w;
    ushort2 c0 = pk2(x0.x, x0.y), c1 = pk2(x0.z, x0.w);
    ushort2 c2 = pk2(x1.x, x1.y), c3 = pk2(x1.z, x1.w);
    w[0]=c0.x; w[1]=c0.y; w[2]=c1.x; w[3]=c1.y;
    w[4]=c2.x; w[5]=c2.y; w[6]=c3.x; w[7]=c3.y;
    *reinterpret_cast<u16x8*>(&wlds[rl*128 + ((j ^ (rl&7))*8)]) = w;
    if (fb && gr < nrows)
      *reinterpret_cast<u16x8*>(fb + grc*128 + j*8) = w;
  }
  __syncthreads();

  f32x4 acc = (f32x4){0.f,0.f,0.f,0.f};
  const int arow = l & 15;
  #pragma unroll
  for (int kk=0;kk<4;++kk){
    int ch = (kk*4 + (l>>4)) ^ (arow & 7);
    bf16x8 a = *reinterpret_cast<const bf16x8*>(&wlds[arow*128 + ch*8]);
    acc = __builtin_amdgcn_mfma_f32_16x16x32_bf16(a, bfrag[kk], acc, 0, 0, 0);
  }

  const int col = l & 15;
  if (col < 4 && (type == 0 || col < 2)){
    #pragma unroll
    for (int i=0;i<4;++i){
      long gr = r0 + (l>>4)*4 + i;
      if (gr < nrows){
        float v = acc[i];
        if (type == 0){
          if (col < 2) el_h[2*gr + col] = v;
          else         er[2*gr + col-2] = v;
        } else if (type == 1){
          el_e[2*gr + col] = v;
        } else {
          el_u[2*gr + col] = v;
        }
      }
    }
  }
}

// ---------------- k4: per-bond exp scores + esum atomics + slot scatter ----------------
__global__ void k4_edgeexp(const int* __restrict__ bsrc, const int* __restrict__ bdst,
                           const float* __restrict__ el_h, const float* __restrict__ er,
                           const float* __restrict__ el_e,
                           int2* __restrict__ slot_bs, float4* __restrict__ slot_e,
                           int* __restrict__ cursor, float* __restrict__ esum){
  int b = blockIdx.x*256 + threadIdx.x;
  if (b >= NB) return;
  int s = bsrc[b], d = bdst[b];
  float2 elh = *reinterpret_cast<const float2*>(&el_h[2*s]);
  float2 erd = *reinterpret_cast<const float2*>(&er[2*d]);
  float2 ele = *reinterpret_cast<const float2*>(&el_e[2*b]);
  float a0 = __expf(lrelu(elh.x + erd.x));
  float a1 = __expf(lrelu(elh.y + erd.y));
  float b0 = __expf(lrelu(ele.x + erd.x));
  float b1 = __expf(lrelu(ele.y + erd.y));
  int pos = atomicAdd(&cursor[d], 1);
  if (pos < CAP){
    slot_bs[(size_t)d*CAP + pos] = make_int2(b, s);
    slot_e [(size_t)d*CAP + pos] = make_float4(a0, a1, b0, b1);
  }
  atomicAdd(&esum[2*d],   a0 + b0);
  atomicAdd(&esum[2*d+1], a1 + b1);
}

// ---------------- kPre: per-atom record + LDS-aggregated degree histogram ----------------
__global__ void kPre(const int* __restrict__ cursor, const float* __restrict__ esum,
                     const float* __restrict__ el_u, const float* __restrict__ er,
                     const int* __restrict__ g2a,
                     float4* __restrict__ recF, int* __restrict__ recC,
                     int* __restrict__ binCnt){
  __shared__ int hcnt[NBINS];
  int t = threadIdx.x;
  if (t < NBINS) hcnt[t] = 0;
  __syncthreads();
  int n = blockIdx.x*256 + t;
  if (n < NA){
    int cc = cursor[n]; cc = cc > CAP ? CAP : cc;
    int g = g2a[n];
    float2 elu = *reinterpret_cast<const float2*>(&el_u[2*g]);
    float2 ern = *reinterpret_cast<const float2*>(&er[2*n]);
    float u0 = __expf(lrelu(elu.x + ern.x));
    float u1 = __expf(lrelu(elu.y + ern.y));
    float iv0 = 1.f/(esum[2*n]   + u0);
    float iv1 = 1.f/(esum[2*n+1] + u1);
    recF[n] = make_float4(iv0, iv1, u0*iv0, u1*iv1);
    recC[n] = cc;
    atomicAdd(&hcnt[cc], 1);           // LDS atomic, 33 words
  }
  __syncthreads();
  if (t < NBINS && hcnt[t] > 0)
    atomicAdd(&binCnt[t], hcnt[t]);    // <=33 global atomics per block
}

// ---------------- kScan: exclusive prefix over 33 degree bins ----------------
__global__ void kScan(const int* __restrict__ binCnt, int* __restrict__ binOff){
  if (threadIdx.x == 0){
    int acc = 0;
    for (int i=0;i<NBINS;++i){ binOff[i] = acc; acc += binCnt[i]; }
  }
}

// ---------------- kScat: two-level counting-sort scatter ----------------
// LDS atomicAdd return value = within-block rank; one global atomic per
// bin per block claims the block's base. No 100k-on-33 contention.
__global__ void kScat(const int* __restrict__ recC, const int* __restrict__ binOff,
                      int* __restrict__ binCur, int* __restrict__ perm){
  __shared__ int hcnt[NBINS];
  __shared__ int base_s[NBINS];
  int t = threadIdx.x;
  if (t < NBINS) hcnt[t] = 0;
  __syncthreads();
  int n = blockIdx.x*256 + t;
  int cc = 0, rank = 0;
  bool valid = (n < NA);
  if (valid){
    cc = recC[n];
    rank = atomicAdd(&hcnt[cc], 1);    // LDS atomic; old value = my rank in block
  }
  __syncthreads();
  if (t < NBINS && hcnt[t] > 0)
    base_s[t] = atomicAdd(&binCur[t], hcnt[t]);   // block's base within bin
  __syncthreads();
  if (valid)
    perm[binOff[cc] + base_s[cc] + rank] = n;
}

// ---------------- kFG v9: v6 structure + degree-sorted atom order ----------------
__global__ __launch_bounds__(512, 4) void kFG(
    const unsigned short* __restrict__ atomB,
    const unsigned short* __restrict__ bondB,
    const int2* __restrict__ slot_bs, const float4* __restrict__ slot_e,
    const float4* __restrict__ recF, const int* __restrict__ recC,
    const int* __restrict__ perm,
    const int* __restrict__ g2a,
    const unsigned short* __restrict__ WcT,
    const unsigned short* __restrict__ P,
    float* __restrict__ out, float* __restrict__ colsum, float* __restrict__ colsq){
  __shared__ unsigned short XA[128*256];   // 64 KB, chunk-XOR swizzled
  __shared__ float au_s[128][2];           // 1 KB
  __shared__ int   prm_s[128];
  const int tid = threadIdx.x;
  const int l  = tid & 63;
  const int li = tid & 15;
  const int gid = tid >> 4;        // 0..31 (group of 16 lanes = one feature row)
  const int w = tid >> 6;          // 0..7
  const int wr = w >> 2, wc = w & 3;
  const int gb = l & 48;           // group base lane within wave
  const int n0 = blockIdx.x * 128;

  f32x4 acc[4][2];
  #pragma unroll
  for (int m=0;m<4;++m)
    #pragma unroll
    for (int nf=0;nf<2;++nf) acc[m][nf] = (f32x4){0.f,0.f,0.f,0.f};

  auto agg = [&](int phase){
    for (int t=0; t<4; ++t){
      int ln = gid + t*32;
      int pn = n0 + ln;
      float a0[8], a1[8];
      #pragma unroll
      for (int k2=0;k2<8;++k2){ a0[k2]=0.f; a1[k2]=0.f; }
      int cc = 0; float iv0=0.f, iv1=0.f;
      int n = 0;
      if (pn < NA){
        n = perm[pn];
        cc = recC[n];
        float4 rec = recF[n];
        iv0 = rec.x; iv1 = rec.y;
        if (phase==0 && li==0){ au_s[ln][0]=rec.z; au_s[ln][1]=rec.w; prm_s[ln]=n; }
      }
      // slot metadata: lanes li cover slots 0..15 (A), li+16 -> 16..31 (B)
      int idxA=0, idxB=0; float w0A=0.f,w1A=0.f,w0B=0.f,w1B=0.f;
      if (li < cc){
        int2 bs = slot_bs[(size_t)n*CAP + li];
        float4 e = slot_e[(size_t)n*CAP + li];
        idxA = phase ? bs.x : bs.y;
        w0A = phase ? e.z : e.x;
        w1A = phase ? e.w : e.y;
      }
      if (li+16 < cc){
        int2 bs = slot_bs[(size_t)n*CAP + li+16];
        float4 e = slot_e[(size_t)n*CAP + li+16];
        idxB = phase ? bs.x : bs.y;
        w0B = phase ? e.z : e.x;
        w1B = phase ? e.w : e.y;
      }
      const unsigned short* tbl = phase ? bondB : atomB;
      if (cc > 0){
        const int last = cc - 1;
        // branchless clamped slot index (loads always valid)
        #define IDXJ(J) ({ int _jj = (J) <= last ? (J) : last; \
                           int _sl = gb + (_jj & 15); \
                           (_jj < 16) ? __shfl(idxA, _sl) : __shfl(idxB, _sl); })
        u16x8 x0 = *reinterpret_cast<const u16x8*>(tbl + (size_t)IDXJ(0)*128 + li*8);
        u16x8 x1 = *reinterpret_cast<const u16x8*>(tbl + (size_t)IDXJ(1)*128 + li*8);
        u16x8 x2 = *reinterpret_cast<const u16x8*>(tbl + (size_t)IDXJ(2)*128 + li*8);
        u16x8 x3 = *reinterpret_cast<const u16x8*>(tbl + (size_t)IDXJ(3)*128 + li*8);
        for (int j0 = 0; j0 < cc; j0 += 4){
          u16x8 y0=x0, y1=x1, y2=x2, y3=x3;
          x0 = *reinterpret_cast<const u16x8*>(tbl + (size_t)IDXJ(j0+4)*128 + li*8);
          x1 = *reinterpret_cast<const u16x8*>(tbl + (size_t)IDXJ(j0+5)*128 + li*8);
          x2 = *reinterpret_cast<const u16x8*>(tbl + (size_t)IDXJ(j0+6)*128 + li*8);
          x3 = *reinterpret_cast<const u16x8*>(tbl + (size_t)IDXJ(j0+7)*128 + li*8);
          #define CONSUME(YY, JJ) { \
            int _j = j0 + (JJ); \
            int _jc = _j <= last ? _j : last; \
            int _sl = gb + (_jc & 15); \
            float _w0 = (_jc < 16) ? __shfl(w0A, _sl) : __shfl(w0B, _sl); \
            float _w1 = (_jc < 16) ? __shfl(w1A, _sl) : __shfl(w1B, _sl); \
            float _c0 = (_j <= last) ? _w0*iv0 : 0.f; \
            float _c1 = (_j <= last) ? _w1*iv1 : 0.f; \
            _Pragma("unroll") \
            for (int k2=0;k2<8;++k2){ \
              float _v = bf2f((YY)[k2]); \
              a0[k2] += _c0*_v; a1[k2] += _c1*_v; \
            } }
          CONSUME(y0, 0)
          CONSUME(y1, 1)
          CONSUME(y2, 2)
          CONSUME(y3, 3)
          #undef CONSUME
        }
        #undef IDXJ
      }
      u16x8 o0, o1;
      #pragma unroll
      for (int k2=0;k2<8;++k2){ o0[k2]=f2bf(a0[k2]); o1[k2]=f2bf(a1[k2]); }
      *reinterpret_cast<u16x8*>(&XA[ln*256 + ((li   ) ^ (ln&7))*8]) = o0;
      *reinterpret_cast<u16x8*>(&XA[ln*256 + ((16+li) ^ (ln&7))*8]) = o1;
    }
  };

  auto gemm = [&](int phase){
    #pragma unroll
    for (int ks=0; ks<8; ++ks){
      bf16x8 av[4], bv[2];
      #pragma unroll
      for (int m=0;m<4;++m){
        int row = wr*64 + m*16 + (l&15);
        int ch = (ks*4 + (l>>4)) ^ (row&7);
        av[m] = *reinterpret_cast<const bf16x8*>(&XA[row*256 + ch*8]);
      }
      #pragma unroll
      for (int nf=0;nf<2;++nf){
        int col = wc*32 + nf*16 + (l&15);
        bv[nf] = *reinterpret_cast<const bf16x8*>(
            WcT + (size_t)col*KDIM + phase*256 + ks*32 + (l>>4)*8);
      }
      #pragma unroll
      for (int m=0;m<4;++m)
        #pragma unroll
        for (int nf=0;nf<2;++nf)
          acc[m][nf] = __builtin_amdgcn_mfma_f32_16x16x32_bf16(av[m], bv[nf], acc[m][nf], 0, 0, 0);
    }
  };

  agg(0);
  __syncthreads();
  gemm(0);
  __syncthreads();
  agg(1);
  __syncthreads();
  gemm(1);

  // epilogue: + global term, store (perm-scattered rows), fused column stats
  float s[2] = {0.f,0.f};
  float q[2] = {0.f,0.f};
  #pragma unroll
  for (int m=0;m<4;++m){
    #pragma unroll
    for (int i=0;i<4;++i){
      int row_l = wr*64 + m*16 + (l>>4)*4 + i;
      int pn = n0 + row_l;
      if (pn < NA){
        size_t row = (size_t)prm_s[row_l];
        float aux = au_s[row_l][0], auy = au_s[row_l][1];
        int g = g2a[row];
        const unsigned short* Pg = P + (size_t)g*256;
        #pragma unroll
        for (int nf=0;nf<2;++nf){
          int col = wc*32 + nf*16 + (l&15);
          float v = acc[m][nf][i] + aux*bf2f(Pg[col]) + auy*bf2f(Pg[128+col]);
          out[row*128 + col] = v;
          s[nf] += v; q[nf] += v*v;
        }
      }
    }
  }
  #pragma unroll
  for (int nf=0;nf<2;++nf){
    int col = wc*32 + nf*16 + (l&15);
    float sv = s[nf], qv = q[nf];
    sv += __shfl_xor(sv, 16); sv += __shfl_xor(sv, 32);
    qv += __shfl_xor(qv, 16); qv += __shfl_xor(qv, 32);
    if (l < 16){
      atomicAdd(&colsum[col], sv);
      atomicAdd(&colsq[col],  qv);
    }
  }
}

// ---------------- k11: BN finalize + apply + ReLU ----------------
__global__ __launch_bounds__(256) void k11_bnrelu(float* __restrict__ out,
                            const float* __restrict__ colsum, const float* __restrict__ colsq,
                            const float* __restrict__ gamma, const float* __restrict__ beta){
  __shared__ float sc[128], sh[128];
  int t = threadIdx.x;
  if (t < 128){
    float mean = colsum[t] / (float)NA;
    float var = fmaxf(colsq[t] / (float)NA - mean*mean, 0.f);
    float s = gamma[t] * rsqrtf(var + 1e-5f);
    sc[t] = s;
    sh[t] = beta[t] - mean*s;
  }
  __syncthreads();
  int i = blockIdx.x*256 + t;   // 3.2M float4s exactly
  float4 v = reinterpret_cast<float4*>(out)[i];
  int c0 = (i*4) & 127;
  v.x = fmaxf(0.f, v.x*sc[c0]   + sh[c0]);
  v.y = fmaxf(0.f, v.y*sc[c0+1] + sh[c0+1]);
  v.z = fmaxf(0.f, v.z*sc[c0+2] + sh[c0+2]);
  v.w = fmaxf(0.f, v.w*sc[c0+3] + sh[c0+3]);
  reinterpret_cast<float4*>(out)[i] = v;
}

extern "C" void kernel_launch(void* const* d_in, const int* in_sizes, int n_in,
                              void* d_out, int out_size, void* d_ws, size_t ws_size,
                              hipStream_t stream) {
  const float* atom = (const float*)d_in[0];
  const float* bond = (const float*)d_in[1];
  const float* glob = (const float*)d_in[2];
  const float* Wa   = (const float*)d_in[3];
  const float* Wb   = (const float*)d_in[4];
  const float* Wg   = (const float*)d_in[5];
  const float* al   = (const float*)d_in[6];
  const float* ar   = (const float*)d_in[7];
  const float* gamma= (const float*)d_in[8];
  const float* beta = (const float*)d_in[9];
  const int* bsrc   = (const int*)d_in[10];
  const int* bdst   = (const int*)d_in[11];
  const int* g2a    = (const int*)d_in[12];
  float* out = (float*)d_out;

  char* base = (char*)d_ws;
  size_t off = 0;
  auto carve = [&](size_t bytes)->void*{
    void* p = base + off;
    off = (off + bytes + 255) & ~(size_t)255;
    return p;
  };
  unsigned short* wTa = (unsigned short*)carve((size_t)16*128*2);
  unsigned short* wTb = (unsigned short*)carve((size_t)16*128*2);
  unsigned short* wTu = (unsigned short*)carve((size_t)16*128*2);
  unsigned short* WcT = (unsigned short*)carve((size_t)128*KDIM*2);
  unsigned short* P   = (unsigned short*)carve((size_t)NG*256*2);
  float* el_h = (float*)carve((size_t)NA*2*4);
  float* er   = (float*)carve((size_t)NA*2*4);
  float* el_e = (float*)carve((size_t)NB*2*4);
  float* el_u = (float*)carve((size_t)NG*2*4);
  float4* recF = (float4*)carve((size_t)NA*16);
  int*    recC = (int*)carve((size_t)NA*4);
  int*    perm = (int*)carve((size_t)NA*4);
  int*    binOff = (int*)carve(64*4);
  // single zero-init region: [esum | cursor | colsum | colsq | binCnt | binCur]
  size_t zbytes = (size_t)NA*2*4 + (size_t)NA*4 + 256*4 + 128*4;
  char* zr = (char*)carve(zbytes);
  float* esum   = (float*)(zr);
  int*   cursor = (int*)(zr + (size_t)NA*2*4);
  float* colsum = (float*)(zr + (size_t)NA*2*4 + (size_t)NA*4);
  float* colsq  = colsum + 128;
  int*   binCnt = (int*)(zr + (size_t)NA*2*4 + (size_t)NA*4 + 256*4);
  int*   binCur = binCnt + 64;
  int2*   slot_bs = (int2*)carve((size_t)NA*CAP*8);
  float4* slot_e  = (float4*)carve((size_t)NA*CAP*16);
  unsigned short* atomB = (unsigned short*)carve((size_t)NA*128*2);
  unsigned short* bondB = (unsigned short*)carve((size_t)NB*128*2);

  hipMemsetAsync(zr, 0, zbytes, stream);

  kW<<<882, 256, 0, stream>>>(Wa, Wb, Wg, glob, al, ar, wTa, wTb, wTu, WcT, P);

  kSC<<<KSC_BLKS, 256, 0, stream>>>(atom, bond, glob, wTa, wTb, wTu,
                                    el_h, er, el_e, el_u, atomB, bondB);

  k4_edgeexp<<<1563, 256, 0, stream>>>(bsrc, bdst, el_h, er, el_e,
                                       slot_bs, slot_e, cursor, esum);

  kPre<<<391, 256, 0, stream>>>(cursor, esum, el_u, er, g2a, recF, recC, binCnt);
  kScan<<<1, 64, 0, stream>>>(binCnt, binOff);
  kScat<<<391, 256, 0, stream>>>(recC, binOff, binCur, perm);

  kFG<<<FG_BLKS, 512, 0, stream>>>(atomB, bondB, slot_bs, slot_e, recF, recC,
                                   perm, g2a, WcT, P, out, colsum, colsq);

  k11_bnrelu<<<12500, 256, 0, stream>>>(out, colsum, colsq, gamma, beta);
}

// Round 17
// 311.501 us; speedup vs baseline: 3.8295x; 1.0687x over previous
//
#include <hip/hip_runtime.h>
#include <hip/hip_bf16.h>

#define NA 100000
#define NB 400000
#define NG 5000
#define NEG 0.2f
#define KDIM 512
#define CAP 32          // max in-degree slots (fixed input graph: 1+Binom; P(>32)~0)
#define FG_BLKS 782     // ceil(NA/128)
#define KSC_BLKS 7891   // ceil(505008/64); covers 505024 row slots

typedef __attribute__((ext_vector_type(8))) short bf16x8;
typedef __attribute__((ext_vector_type(8))) unsigned short u16x8;
typedef __attribute__((ext_vector_type(4))) float f32x4;

__device__ __forceinline__ float lrelu(float x){ return x > 0.f ? x : NEG*x; }
__device__ __forceinline__ unsigned short f2bf(float f){
  unsigned u = __float_as_uint(f);
  u = (u + 0x7FFFu + ((u>>16)&1u)) >> 16;
  return (unsigned short)u;
}
__device__ __forceinline__ float bf2f(unsigned short s){
  return __uint_as_float(((unsigned)s) << 16);
}
__device__ __forceinline__ ushort2 pk2(float x, float y){
  __hip_bfloat162 t = __float22bfloat162_rn(make_float2(x, y));
  return *reinterpret_cast<ushort2*>(&t);
}

// ---------------- kW: weight prep ----------------
__global__ void kW(const float* __restrict__ Wa, const float* __restrict__ Wb,
                   const float* __restrict__ Wg, const float* __restrict__ glob,
                   const float* __restrict__ al, const float* __restrict__ ar,
                   unsigned short* wTa, unsigned short* wTb, unsigned short* wTu,
                   unsigned short* WcT, unsigned short* P){
  int blk = blockIdx.x;
  int tid = threadIdx.x;
  if (blk == 0){
    int k = tid >> 1, h = tid & 1;
    const float* wa = Wa + k*256 + h*128;
    const float* wb = Wb + k*256 + h*128;
    const float* wg = Wg + k*256 + h*128;
    const float* pl = al + h*128;
    const float* pr = ar + h*128;
    float sa=0.f, sra=0.f, se=0.f, su=0.f;
    for (int d=0; d<128; ++d){
      float L = pl[d], R = pr[d];
      sa  += wa[d]*L;  sra += wa[d]*R;
      se  += wb[d]*L;  su  += wg[d]*L;
    }
    wTa[h*128 + k]     = f2bf(sa);
    wTa[(2+h)*128 + k] = f2bf(sra);
    wTb[h*128 + k]     = f2bf(se);
    wTu[h*128 + k]     = f2bf(su);
    for (int idx = tid; idx < 14*128; idx += 256){
      int c = 2 + (idx >> 7), k2 = idx & 127;
      wTb[c*128 + k2] = 0;
      wTu[c*128 + k2] = 0;
      if (c >= 4) wTa[c*128 + k2] = 0;
    }
  } else if (blk <= 256){
    int idx = (blk-1)*256 + tid;            // 65536 = 128*KDIM
    int c = idx / KDIM, j = idx % KDIM;
    int part = j >> 7, k = j & 127;
    const float* W = (part < 2) ? Wa : Wb;
    int h = part & 1;
    WcT[(size_t)c*KDIM + j] = f2bf(0.5f * W[k*256 + h*128 + c]);
  } else {
    __shared__ float gl[8][128];
    int g0 = (blk-257)*8;                   // 625 blocks
    #pragma unroll
    for (int r=0;r<4;++r){
      int idx = r*256+tid;
      gl[idx>>7][idx&127] = glob[(size_t)(g0 + (idx>>7))*128 + (idx&127)];
    }
    __syncthreads();
    float acc[8];
    #pragma unroll
    for (int g=0;g<8;++g) acc[g]=0.f;
    for (int k=0;k<128;++k){
      float wv = Wg[k*256 + tid];
      #pragma unroll
      for (int g=0;g<8;++g) acc[g] += gl[g][k]*wv;
    }
    #pragma unroll
    for (int g=0;g<8;++g)
      P[(size_t)(g0+g)*256 + tid] = f2bf(0.5f*acc[g]);
  }
}

// ---------------- kSC: fused convert + MFMA score GEMM ----------------
__global__ __launch_bounds__(256) void kSC(
    const float* __restrict__ atom, const float* __restrict__ bond,
    const float* __restrict__ glob,
    const unsigned short* __restrict__ wTa, const unsigned short* __restrict__ wTb,
    const unsigned short* __restrict__ wTu,
    float* __restrict__ el_h, float* __restrict__ er,
    float* __restrict__ el_e, float* __restrict__ el_u,
    unsigned short* __restrict__ atomB, unsigned short* __restrict__ bondB){
  __shared__ unsigned short lds[4][16*128];   // 16 KB
  const int wid = threadIdx.x >> 6;
  const int l = threadIdx.x & 63;
  const long rowbase = ((long)blockIdx.x*4 + wid) * 16;

  const float* feats; const unsigned short* wT; unsigned short* fb;
  long r0; long nrows; int type;
  if (rowbase < NA){            feats = atom; wT = wTa; fb = atomB; r0 = rowbase;          nrows = NA; type = 0; }
  else if (rowbase < NA+NB){    feats = bond; wT = wTb; fb = bondB; r0 = rowbase-NA;       nrows = NB; type = 1; }
  else {                        feats = glob; wT = wTu; fb = nullptr; r0 = rowbase-(NA+NB); nrows = NG; type = 2; }

  bf16x8 bfrag[4];
  #pragma unroll
  for (int kk=0;kk<4;++kk)
    bfrag[kk] = *reinterpret_cast<const bf16x8*>(wT + (size_t)(l&15)*128 + kk*32 + (l>>4)*8);

  unsigned short* wlds = lds[wid];
  const int j = l & 15;       // 8-elem chunk within row
  const int rl0 = l >> 4;     // row subgroup
  #pragma unroll
  for (int i=0;i<4;++i){
    int rl = rl0 + i*4;                    // local row 0..15
    long gr = r0 + rl;
    long grc = gr < nrows ? gr : (nrows-1);
    const float* src = feats + grc*128 + j*8;
    float4 x0 = *reinterpret_cast<const float4*>(src);
    float4 x1 = *reinterpret_cast<const float4*>(src+4);
    u16x8 w;
    ushort2 c0 = pk2(x0.x, x0.y), c1 = pk2(x0.z, x0.w);
    ushort2 c2 = pk2(x1.x, x1.y), c3 = pk2(x1.z, x1.w);
    w[0]=c0.x; w[1]=c0.y; w[2]=c1.x; w[3]=c1.y;
    w[4]=c2.x; w[5]=c2.y; w[6]=c3.x; w[7]=c3.y;
    *reinterpret_cast<u16x8*>(&wlds[rl*128 + ((j ^ (rl&7))*8)]) = w;
    if (fb && gr < nrows)
      *reinterpret_cast<u16x8*>(fb + grc*128 + j*8) = w;
  }
  __syncthreads();

  f32x4 acc = (f32x4){0.f,0.f,0.f,0.f};
  const int arow = l & 15;
  #pragma unroll
  for (int kk=0;kk<4;++kk){
    int ch = (kk*4 + (l>>4)) ^ (arow & 7);
    bf16x8 a = *reinterpret_cast<const bf16x8*>(&wlds[arow*128 + ch*8]);
    acc = __builtin_amdgcn_mfma_f32_16x16x32_bf16(a, bfrag[kk], acc, 0, 0, 0);
  }

  const int col = l & 15;
  if (col < 4 && (type == 0 || col < 2)){
    #pragma unroll
    for (int i=0;i<4;++i){
      long gr = r0 + (l>>4)*4 + i;
      if (gr < nrows){
        float v = acc[i];
        if (type == 0){
          if (col < 2) el_h[2*gr + col] = v;
          else         er[2*gr + col-2] = v;
        } else if (type == 1){
          el_e[2*gr + col] = v;
        } else {
          el_u[2*gr + col] = v;
        }
      }
    }
  }
}

// ---------------- k4: per-bond exp scores + esum atomics + slot scatter ----------------
__global__ void k4_edgeexp(const int* __restrict__ bsrc, const int* __restrict__ bdst,
                           const float* __restrict__ el_h, const float* __restrict__ er,
                           const float* __restrict__ el_e,
                           int2* __restrict__ slot_bs, float4* __restrict__ slot_e,
                           int* __restrict__ cursor, float* __restrict__ esum){
  int b = blockIdx.x*256 + threadIdx.x;
  if (b >= NB) return;
  int s = bsrc[b], d = bdst[b];
  float2 elh = *reinterpret_cast<const float2*>(&el_h[2*s]);
  float2 erd = *reinterpret_cast<const float2*>(&er[2*d]);
  float2 ele = *reinterpret_cast<const float2*>(&el_e[2*b]);
  float a0 = __expf(lrelu(elh.x + erd.x));
  float a1 = __expf(lrelu(elh.y + erd.y));
  float b0 = __expf(lrelu(ele.x + erd.x));
  float b1 = __expf(lrelu(ele.y + erd.y));
  int pos = atomicAdd(&cursor[d], 1);
  if (pos < CAP){
    slot_bs[(size_t)d*CAP + pos] = make_int2(b, s);
    slot_e [(size_t)d*CAP + pos] = make_float4(a0, a1, b0, b1);
  }
  atomicAdd(&esum[2*d],   a0 + b0);
  atomicAdd(&esum[2*d+1], a1 + b1);
}

// ---------------- kPre: per-atom record {iv0, iv1, au0, au1} + cc ----------------
__global__ void kPre(const int* __restrict__ cursor, const float* __restrict__ esum,
                     const float* __restrict__ el_u, const float* __restrict__ er,
                     const int* __restrict__ g2a,
                     float4* __restrict__ recF, int* __restrict__ recC){
  int n = blockIdx.x*256 + threadIdx.x;
  if (n >= NA) return;
  int cc = cursor[n]; cc = cc > CAP ? CAP : cc;
  int g = g2a[n];
  float2 elu = *reinterpret_cast<const float2*>(&el_u[2*g]);
  float2 ern = *reinterpret_cast<const float2*>(&er[2*n]);
  float u0 = __expf(lrelu(elu.x + ern.x));
  float u1 = __expf(lrelu(elu.y + ern.y));
  float iv0 = 1.f/(esum[2*n]   + u0);
  float iv1 = 1.f/(esum[2*n+1] + u1);
  recF[n] = make_float4(iv0, iv1, u0*iv0, u1*iv1);
  recC[n] = cc;
}

// ---------------- kFG v6 (measured best): fused aggregation + MFMA GEMM ----------------
// BM=128, XA[128][256] reused across phase A/B, 4-deep branchless gather
// pipeline, per-atom {iv,au,cc} from kPre. 142us measured (R12); 7 structural
// variants all land 142-160us -> empirical random-row-gather plateau.
__global__ __launch_bounds__(512, 4) void kFG(
    const unsigned short* __restrict__ atomB,
    const unsigned short* __restrict__ bondB,
    const int2* __restrict__ slot_bs, const float4* __restrict__ slot_e,
    const float4* __restrict__ recF, const int* __restrict__ recC,
    const int* __restrict__ g2a,
    const unsigned short* __restrict__ WcT,
    const unsigned short* __restrict__ P,
    float* __restrict__ out, float* __restrict__ colsum, float* __restrict__ colsq){
  __shared__ unsigned short XA[128*256];   // 64 KB, chunk-XOR swizzled
  __shared__ float au_s[128][2];           // 1 KB
  const int tid = threadIdx.x;
  const int l  = tid & 63;
  const int li = tid & 15;
  const int gid = tid >> 4;        // 0..31 (group of 16 lanes = one feature row)
  const int w = tid >> 6;          // 0..7
  const int wr = w >> 2, wc = w & 3;
  const int gb = l & 48;           // group base lane within wave
  const int n0 = blockIdx.x * 128;

  f32x4 acc[4][2];
  #pragma unroll
  for (int m=0;m<4;++m)
    #pragma unroll
    for (int nf=0;nf<2;++nf) acc[m][nf] = (f32x4){0.f,0.f,0.f,0.f};

  auto agg = [&](int phase){
    for (int t=0; t<4; ++t){
      int ln = gid + t*32;
      int n = n0 + ln;
      float a0[8], a1[8];
      #pragma unroll
      for (int k2=0;k2<8;++k2){ a0[k2]=0.f; a1[k2]=0.f; }
      int cc = 0; float iv0=0.f, iv1=0.f;
      if (n < NA){
        cc = recC[n];
        float4 rec = recF[n];
        iv0 = rec.x; iv1 = rec.y;
        if (phase==0 && li==0){ au_s[ln][0]=rec.z; au_s[ln][1]=rec.w; }
      }
      // slot metadata: lanes li cover slots 0..15 (A), li+16 -> 16..31 (B)
      int idxA=0, idxB=0; float w0A=0.f,w1A=0.f,w0B=0.f,w1B=0.f;
      if (li < cc){
        int2 bs = slot_bs[(size_t)n*CAP + li];
        float4 e = slot_e[(size_t)n*CAP + li];
        idxA = phase ? bs.x : bs.y;
        w0A = phase ? e.z : e.x;
        w1A = phase ? e.w : e.y;
      }
      if (li+16 < cc){
        int2 bs = slot_bs[(size_t)n*CAP + li+16];
        float4 e = slot_e[(size_t)n*CAP + li+16];
        idxB = phase ? bs.x : bs.y;
        w0B = phase ? e.z : e.x;
        w1B = phase ? e.w : e.y;
      }
      const unsigned short* tbl = phase ? bondB : atomB;
      if (cc > 0){
        const int last = cc - 1;
        // branchless clamped slot index (loads always valid)
        #define IDXJ(J) ({ int _jj = (J) <= last ? (J) : last; \
                           int _sl = gb + (_jj & 15); \
                           (_jj < 16) ? __shfl(idxA, _sl) : __shfl(idxB, _sl); })
        u16x8 x0 = *reinterpret_cast<const u16x8*>(tbl + (size_t)IDXJ(0)*128 + li*8);
        u16x8 x1 = *reinterpret_cast<const u16x8*>(tbl + (size_t)IDXJ(1)*128 + li*8);
        u16x8 x2 = *reinterpret_cast<const u16x8*>(tbl + (size_t)IDXJ(2)*128 + li*8);
        u16x8 x3 = *reinterpret_cast<const u16x8*>(tbl + (size_t)IDXJ(3)*128 + li*8);
        for (int j0 = 0; j0 < cc; j0 += 4){
          u16x8 y0=x0, y1=x1, y2=x2, y3=x3;
          x0 = *reinterpret_cast<const u16x8*>(tbl + (size_t)IDXJ(j0+4)*128 + li*8);
          x1 = *reinterpret_cast<const u16x8*>(tbl + (size_t)IDXJ(j0+5)*128 + li*8);
          x2 = *reinterpret_cast<const u16x8*>(tbl + (size_t)IDXJ(j0+6)*128 + li*8);
          x3 = *reinterpret_cast<const u16x8*>(tbl + (size_t)IDXJ(j0+7)*128 + li*8);
          #define CONSUME(YY, JJ) { \
            int _j = j0 + (JJ); \
            int _jc = _j <= last ? _j : last; \
            int _sl = gb + (_jc & 15); \
            float _w0 = (_jc < 16) ? __shfl(w0A, _sl) : __shfl(w0B, _sl); \
            float _w1 = (_jc < 16) ? __shfl(w1A, _sl) : __shfl(w1B, _sl); \
            float _c0 = (_j <= last) ? _w0*iv0 : 0.f; \
            float _c1 = (_j <= last) ? _w1*iv1 : 0.f; \
            _Pragma("unroll") \
            for (int k2=0;k2<8;++k2){ \
              float _v = bf2f((YY)[k2]); \
              a0[k2] += _c0*_v; a1[k2] += _c1*_v; \
            } }
          CONSUME(y0, 0)
          CONSUME(y1, 1)
          CONSUME(y2, 2)
          CONSUME(y3, 3)
          #undef CONSUME
        }
        #undef IDXJ
      }
      u16x8 o0, o1;
      #pragma unroll
      for (int k2=0;k2<8;++k2){ o0[k2]=f2bf(a0[k2]); o1[k2]=f2bf(a1[k2]); }
      *reinterpret_cast<u16x8*>(&XA[ln*256 + ((li   ) ^ (ln&7))*8]) = o0;
      *reinterpret_cast<u16x8*>(&XA[ln*256 + ((16+li) ^ (ln&7))*8]) = o1;
    }
  };

  auto gemm = [&](int phase){
    #pragma unroll
    for (int ks=0; ks<8; ++ks){
      bf16x8 av[4], bv[2];
      #pragma unroll
      for (int m=0;m<4;++m){
        int row = wr*64 + m*16 + (l&15);
        int ch = (ks*4 + (l>>4)) ^ (row&7);
        av[m] = *reinterpret_cast<const bf16x8*>(&XA[row*256 + ch*8]);
      }
      #pragma unroll
      for (int nf=0;nf<2;++nf){
        int col = wc*32 + nf*16 + (l&15);
        bv[nf] = *reinterpret_cast<const bf16x8*>(
            WcT + (size_t)col*KDIM + phase*256 + ks*32 + (l>>4)*8);
      }
      #pragma unroll
      for (int m=0;m<4;++m)
        #pragma unroll
        for (int nf=0;nf<2;++nf)
          acc[m][nf] = __builtin_amdgcn_mfma_f32_16x16x32_bf16(av[m], bv[nf], acc[m][nf], 0, 0, 0);
    }
  };

  agg(0);
  __syncthreads();
  gemm(0);
  __syncthreads();
  agg(1);
  __syncthreads();
  gemm(1);

  // epilogue: + global term, store, fused column stats
  float s[2] = {0.f,0.f};
  float q[2] = {0.f,0.f};
  #pragma unroll
  for (int m=0;m<4;++m){
    #pragma unroll
    for (int i=0;i<4;++i){
      int row_l = wr*64 + m*16 + (l>>4)*4 + i;
      size_t row = (size_t)n0 + row_l;
      if (row < NA){
        float aux = au_s[row_l][0], auy = au_s[row_l][1];
        int g = g2a[row];
        const unsigned short* Pg = P + (size_t)g*256;
        #pragma unroll
        for (int nf=0;nf<2;++nf){
          int col = wc*32 + nf*16 + (l&15);
          float v = acc[m][nf][i] + aux*bf2f(Pg[col]) + auy*bf2f(Pg[128+col]);
          out[row*128 + col] = v;
          s[nf] += v; q[nf] += v*v;
        }
      }
    }
  }
  #pragma unroll
  for (int nf=0;nf<2;++nf){
    int col = wc*32 + nf*16 + (l&15);
    float sv = s[nf], qv = q[nf];
    sv += __shfl_xor(sv, 16); sv += __shfl_xor(sv, 32);
    qv += __shfl_xor(qv, 16); qv += __shfl_xor(qv, 32);
    if (l < 16){
      atomicAdd(&colsum[col], sv);
      atomicAdd(&colsq[col],  qv);
    }
  }
}

// ---------------- k11: BN finalize + apply + ReLU ----------------
__global__ __launch_bounds__(256) void k11_bnrelu(float* __restrict__ out,
                            const float* __restrict__ colsum, const float* __restrict__ colsq,
                            const float* __restrict__ gamma, const float* __restrict__ beta){
  __shared__ float sc[128], sh[128];
  int t = threadIdx.x;
  if (t < 128){
    float mean = colsum[t] / (float)NA;
    float var = fmaxf(colsq[t] / (float)NA - mean*mean, 0.f);
    float s = gamma[t] * rsqrtf(var + 1e-5f);
    sc[t] = s;
    sh[t] = beta[t] - mean*s;
  }
  __syncthreads();
  int i = blockIdx.x*256 + t;   // 3.2M float4s exactly
  float4 v = reinterpret_cast<float4*>(out)[i];
  int c0 = (i*4) & 127;
  v.x = fmaxf(0.f, v.x*sc[c0]   + sh[c0]);
  v.y = fmaxf(0.f, v.y*sc[c0+1] + sh[c0+1]);
  v.z = fmaxf(0.f, v.z*sc[c0+2] + sh[c0+2]);
  v.w = fmaxf(0.f, v.w*sc[c0+3] + sh[c0+3]);
  reinterpret_cast<float4*>(out)[i] = v;
}

extern "C" void kernel_launch(void* const* d_in, const int* in_sizes, int n_in,
                              void* d_out, int out_size, void* d_ws, size_t ws_size,
                              hipStream_t stream) {
  const float* atom = (const float*)d_in[0];
  const float* bond = (const float*)d_in[1];
  const float* glob = (const float*)d_in[2];
  const float* Wa   = (const float*)d_in[3];
  const float* Wb   = (const float*)d_in[4];
  const float* Wg   = (const float*)d_in[5];
  const float* al   = (const float*)d_in[6];
  const float* ar   = (const float*)d_in[7];
  const float* gamma= (const float*)d_in[8];
  const float* beta = (const float*)d_in[9];
  const int* bsrc   = (const int*)d_in[10];
  const int* bdst   = (const int*)d_in[11];
  const int* g2a    = (const int*)d_in[12];
  float* out = (float*)d_out;

  char* base = (char*)d_ws;
  size_t off = 0;
  auto carve = [&](size_t bytes)->void*{
    void* p = base + off;
    off = (off + bytes + 255) & ~(size_t)255;
    return p;
  };
  unsigned short* wTa = (unsigned short*)carve((size_t)16*128*2);
  unsigned short* wTb = (unsigned short*)carve((size_t)16*128*2);
  unsigned short* wTu = (unsigned short*)carve((size_t)16*128*2);
  unsigned short* WcT = (unsigned short*)carve((size_t)128*KDIM*2);
  unsigned short* P   = (unsigned short*)carve((size_t)NG*256*2);
  float* el_h = (float*)carve((size_t)NA*2*4);
  float* er   = (float*)carve((size_t)NA*2*4);
  float* el_e = (float*)carve((size_t)NB*2*4);
  float* el_u = (float*)carve((size_t)NG*2*4);
  float4* recF = (float4*)carve((size_t)NA*16);
  int*    recC = (int*)carve((size_t)NA*4);
  // single zero-init region: [esum | cursor | colsum | colsq]
  char* zr = (char*)carve((size_t)NA*2*4 + (size_t)NA*4 + 256*4);
  float* esum   = (float*)(zr);
  int*   cursor = (int*)(zr + (size_t)NA*2*4);
  float* colsum = (float*)(zr + (size_t)NA*2*4 + (size_t)NA*4);
  float* colsq  = colsum + 128;
  size_t zbytes = (size_t)NA*2*4 + (size_t)NA*4 + 256*4;
  int2*   slot_bs = (int2*)carve((size_t)NA*CAP*8);
  float4* slot_e  = (float4*)carve((size_t)NA*CAP*16);
  unsigned short* atomB = (unsigned short*)carve((size_t)NA*128*2);
  unsigned short* bondB = (unsigned short*)carve((size_t)NB*128*2);

  hipMemsetAsync(zr, 0, zbytes, stream);

  kW<<<882, 256, 0, stream>>>(Wa, Wb, Wg, glob, al, ar, wTa, wTb, wTu, WcT, P);

  kSC<<<KSC_BLKS, 256, 0, stream>>>(atom, bond, glob, wTa, wTb, wTu,
                                    el_h, er, el_e, el_u, atomB, bondB);

  k4_edgeexp<<<1563, 256, 0, stream>>>(bsrc, bdst, el_h, er, el_e,
                                       slot_bs, slot_e, cursor, esum);

  kPre<<<391, 256, 0, stream>>>(cursor, esum, el_u, er, g2a, recF, recC);

  kFG<<<FG_BLKS, 512, 0, stream>>>(atomB, bondB, slot_bs, slot_e, recF, recC,
                                   g2a, WcT, P, out, colsum, colsq);

  k11_bnrelu<<<12500, 256, 0, stream>>>(out, colsum, colsq, gamma, beta);
}